// Round 1
// baseline (743.197 us; speedup 1.0000x reference)
//
#include <hip/hip_runtime.h>
#include <hip/hip_bf16.h>
#include <math.h>

#define BB 16
#define TT 2048
#define CC 1024
#define HH 64
#define BT (BB*TT)

// ---------------------------------------------------------------------------
// Kernel 1: QKV projection.  (BT x 1024) @ (1024 x 64) x3  -> q,k,v fp32.
// Block: 256 threads computes 64 rows x 192 cols. K chunked by 32.
// LDS: xs[64][36] (pad 36: row stride 144B, 16B aligned), ws[32][196].
// ---------------------------------------------------------------------------
__global__ __launch_bounds__(256) void qkv_kernel(
    const float* __restrict__ x,
    const float* __restrict__ Wq, const float* __restrict__ bq,
    const float* __restrict__ Wk, const float* __restrict__ bk,
    const float* __restrict__ Wv, const float* __restrict__ bv,
    float* __restrict__ qo, float* __restrict__ ko, float* __restrict__ vo)
{
    __shared__ float xs[64][36];
    __shared__ float ws[32][196];
    const int tid = threadIdx.x;
    const int ty = tid >> 4, tx = tid & 15;
    const int row0 = blockIdx.x * 64;

    float acc[4][12];
#pragma unroll
    for (int i = 0; i < 4; ++i)
#pragma unroll
        for (int j = 0; j < 12; ++j) acc[i][j] = 0.f;

    const float* Wm[3] = {Wq, Wk, Wv};

    for (int kc = 0; kc < 32; ++kc) {
        __syncthreads();
        // x chunk: 64 rows x 32 k  (512 float4, 2 per thread)
#pragma unroll
        for (int p = 0; p < 2; ++p) {
            int li = tid + p * 256;
            int r = li >> 3, k4 = li & 7;
            float4 xv = *(const float4*)(x + (size_t)(row0 + r) * CC + kc * 32 + k4 * 4);
            *(float4*)&xs[r][k4 * 4] = xv;
        }
        // W chunks: 3 x (32 k x 64 c)
#pragma unroll
        for (int m = 0; m < 3; ++m) {
#pragma unroll
            for (int p = 0; p < 2; ++p) {
                int li = tid + p * 256;
                int kk = li >> 4, c4 = li & 15;
                float4 wv = *(const float4*)(Wm[m] + (size_t)(kc * 32 + kk) * HH + c4 * 4);
                *(float4*)&ws[kk][m * 64 + c4 * 4] = wv;
            }
        }
        __syncthreads();

#pragma unroll
        for (int k4 = 0; k4 < 8; ++k4) {
            float as_[4][4];
#pragma unroll
            for (int i = 0; i < 4; ++i) {
                float4 av = *(const float4*)&xs[ty * 4 + i][k4 * 4];
                as_[i][0] = av.x; as_[i][1] = av.y; as_[i][2] = av.z; as_[i][3] = av.w;
            }
#pragma unroll
            for (int c = 0; c < 4; ++c) {
                const float4* wrow = (const float4*)&ws[k4 * 4 + c][0];
                float4 b0 = wrow[tx * 3 + 0];
                float4 b1 = wrow[tx * 3 + 1];
                float4 b2 = wrow[tx * 3 + 2];
                float bs_[12] = {b0.x, b0.y, b0.z, b0.w, b1.x, b1.y, b1.z, b1.w,
                                 b2.x, b2.y, b2.z, b2.w};
#pragma unroll
                for (int i = 0; i < 4; ++i)
#pragma unroll
                    for (int j = 0; j < 12; ++j)
                        acc[i][j] += as_[i][c] * bs_[j];
            }
        }
    }

    // epilogue: bias + scatter store to the right q/k/v matrix
#pragma unroll
    for (int i = 0; i < 4; ++i) {
        size_t r = (size_t)(row0 + ty * 4 + i);
#pragma unroll
        for (int j = 0; j < 12; ++j) {
            int cfull = tx * 12 + j;
            int m = cfull >> 6;
            int h = cfull & 63;
            float bias = (m == 0 ? bq[h] : (m == 1 ? bk[h] : bv[h]));
            float* po = (m == 0 ? qo : (m == 1 ? ko : vo));
            po[r * HH + h] = acc[i][j] + bias;
        }
    }
}

// ---------------------------------------------------------------------------
// Kernel 2: per-column softmax stats over the QUERY axis.
// Block: (batch b, 64 columns s). Iterates t-tiles (64) from the diagonal.
// Scores via LDS GEMM (q[t][d] x k^T[d][s]), per-thread online (m,d) for its
// 4 columns, merged across the 16 ty rows at the end.
// ---------------------------------------------------------------------------
__global__ __launch_bounds__(256) void colstats_kernel(
    const float* __restrict__ q, const float* __restrict__ k,
    float* __restrict__ mcol, float* __restrict__ dcol)
{
    __shared__ float klds[64][68];   // [d][s]  (transposed)
    __shared__ float qlds[64][68];   // [t][d]
    __shared__ float2 red[16][64];
    const int tid = threadIdx.x;
    const int ty = tid >> 4, tx = tid & 15;
    const int s_tile = blockIdx.x, b = blockIdx.y;
    const int s0 = s_tile * 64;
    const float* kbase = k + ((size_t)b * TT + s0) * HH;
    const float* qbase = q + (size_t)b * TT * HH;

    // k tile, transposed into [d][s]
#pragma unroll
    for (int p = 0; p < 4; ++p) {
        int li = tid + p * 256;
        int s = li >> 4, d4 = li & 15;
        float4 kv = *(const float4*)(kbase + (size_t)s * HH + d4 * 4);
        klds[d4 * 4 + 0][s] = kv.x; klds[d4 * 4 + 1][s] = kv.y;
        klds[d4 * 4 + 2][s] = kv.z; klds[d4 * 4 + 3][s] = kv.w;
    }

    float mj[4], dj[4];
#pragma unroll
    for (int j = 0; j < 4; ++j) { mj[j] = -INFINITY; dj[j] = 0.f; }

    for (int tt = s_tile; tt < TT / 64; ++tt) {
        __syncthreads();
#pragma unroll
        for (int p = 0; p < 4; ++p) {
            int li = tid + p * 256;
            int t = li >> 4, d4 = li & 15;
            *(float4*)&qlds[t][d4 * 4] =
                *(const float4*)(qbase + (size_t)(tt * 64 + t) * HH + d4 * 4);
        }
        __syncthreads();

        float acc[4][4];
#pragma unroll
        for (int i = 0; i < 4; ++i)
#pragma unroll
            for (int j = 0; j < 4; ++j) acc[i][j] = 0.f;

#pragma unroll 4
        for (int d4 = 0; d4 < 16; ++d4) {
            float as_[4][4], ks_[4][4];
#pragma unroll
            for (int i = 0; i < 4; ++i) {
                float4 av = *(const float4*)&qlds[ty * 4 + i][d4 * 4];
                as_[i][0] = av.x; as_[i][1] = av.y; as_[i][2] = av.z; as_[i][3] = av.w;
            }
#pragma unroll
            for (int c = 0; c < 4; ++c) {
                float4 kv = *(const float4*)&klds[d4 * 4 + c][tx * 4];
                ks_[c][0] = kv.x; ks_[c][1] = kv.y; ks_[c][2] = kv.z; ks_[c][3] = kv.w;
            }
#pragma unroll
            for (int i = 0; i < 4; ++i)
#pragma unroll
                for (int j = 0; j < 4; ++j)
#pragma unroll
                    for (int c = 0; c < 4; ++c)
                        acc[i][j] += as_[i][c] * ks_[c][j];
        }

        if (tt == s_tile) {  // diagonal tile: keep t >= s only
#pragma unroll
            for (int i = 0; i < 4; ++i)
#pragma unroll
                for (int j = 0; j < 4; ++j)
                    if (ty * 4 + i < tx * 4 + j) acc[i][j] = -INFINITY;
        }

#pragma unroll
        for (int j = 0; j < 4; ++j) {
            float tmax = fmaxf(fmaxf(acc[0][j], acc[1][j]), fmaxf(acc[2][j], acc[3][j]));
            if (tmax != -INFINITY) {
                float nm = fmaxf(mj[j], tmax);
                float s = dj[j] * expf(mj[j] - nm);  // mj=-inf -> 0*0 = 0
                s += expf(acc[0][j] - nm) + expf(acc[1][j] - nm)
                   + expf(acc[2][j] - nm) + expf(acc[3][j] - nm);
                mj[j] = nm; dj[j] = s;
            }
        }
    }

    __syncthreads();
#pragma unroll
    for (int j = 0; j < 4; ++j) red[ty][tx * 4 + j] = make_float2(mj[j], dj[j]);
    __syncthreads();
    if (tid < 64) {
        float2 pr[16];
#pragma unroll
        for (int r = 0; r < 16; ++r) pr[r] = red[r][tid];
        float M = -INFINITY;
#pragma unroll
        for (int r = 0; r < 16; ++r) M = fmaxf(M, pr[r].x);
        float D = 0.f;
#pragma unroll
        for (int r = 0; r < 16; ++r) D += pr[r].y * expf(pr[r].x - M);
        mcol[(size_t)b * TT + s0 + tid] = M;
        dcol[(size_t)b * TT + s0 + tid] = D;
    }
}

// ---------------------------------------------------------------------------
// Kernel 3: out[t,:] = sum_{s<=t} exp(S[t,s]-m[s]) * (v[s,:]/D[s]).
// Block: (b, 64-row t-tile). Per s-tile: GEMM1 scores -> e (into LDS, reusing
// the k buffer) -> GEMM2 accumulate into registers.
// ---------------------------------------------------------------------------
__global__ __launch_bounds__(256) void attnout_kernel(
    const float* __restrict__ q, const float* __restrict__ k,
    const float* __restrict__ v,
    const float* __restrict__ mcol, const float* __restrict__ dcol,
    float* __restrict__ out)
{
    __shared__ float qlds[64][68];   // [t][d]
    __shared__ float alds[64][68];   // k as [d][s], then e as [t][s]
    __shared__ float vlds[64][68];   // [s][d], pre-divided by D[s]
    const int tid = threadIdx.x;
    const int ty = tid >> 4, tx = tid & 15;
    const int t_tile = blockIdx.x, b = blockIdx.y;
    const int t0 = t_tile * 64;
    const float* qb = q + (size_t)b * TT * HH;
    const float* kb = k + (size_t)b * TT * HH;
    const float* vb = v + (size_t)b * TT * HH;

#pragma unroll
    for (int p = 0; p < 4; ++p) {
        int li = tid + p * 256;
        int t = li >> 4, d4 = li & 15;
        *(float4*)&qlds[t][d4 * 4] = *(const float4*)(qb + (size_t)(t0 + t) * HH + d4 * 4);
    }

    float oacc[4][4];
#pragma unroll
    for (int i = 0; i < 4; ++i)
#pragma unroll
        for (int j = 0; j < 4; ++j) oacc[i][j] = 0.f;

    for (int ss = 0; ss <= t_tile; ++ss) {
        const int s0 = ss * 64;
        __syncthreads();   // prev GEMM2 reads done (also covers initial q load)
#pragma unroll
        for (int p = 0; p < 4; ++p) {
            int li = tid + p * 256;
            int s = li >> 4, d4 = li & 15;
            float4 kv = *(const float4*)(kb + (size_t)(s0 + s) * HH + d4 * 4);
            alds[d4 * 4 + 0][s] = kv.x; alds[d4 * 4 + 1][s] = kv.y;
            alds[d4 * 4 + 2][s] = kv.z; alds[d4 * 4 + 3][s] = kv.w;
            float invd = 1.f / dcol[(size_t)b * TT + s0 + s];
            float4 vv = *(const float4*)(vb + (size_t)(s0 + s) * HH + d4 * 4);
            vv.x *= invd; vv.y *= invd; vv.z *= invd; vv.w *= invd;
            *(float4*)&vlds[s][d4 * 4] = vv;
        }
        __syncthreads();

        // GEMM1: scores
        float acc[4][4];
#pragma unroll
        for (int i = 0; i < 4; ++i)
#pragma unroll
            for (int j = 0; j < 4; ++j) acc[i][j] = 0.f;
#pragma unroll 4
        for (int d4 = 0; d4 < 16; ++d4) {
            float as_[4][4], ks_[4][4];
#pragma unroll
            for (int i = 0; i < 4; ++i) {
                float4 av = *(const float4*)&qlds[ty * 4 + i][d4 * 4];
                as_[i][0] = av.x; as_[i][1] = av.y; as_[i][2] = av.z; as_[i][3] = av.w;
            }
#pragma unroll
            for (int c = 0; c < 4; ++c) {
                float4 kv = *(const float4*)&alds[d4 * 4 + c][tx * 4];
                ks_[c][0] = kv.x; ks_[c][1] = kv.y; ks_[c][2] = kv.z; ks_[c][3] = kv.w;
            }
#pragma unroll
            for (int i = 0; i < 4; ++i)
#pragma unroll
                for (int j = 0; j < 4; ++j)
#pragma unroll
                    for (int c = 0; c < 4; ++c)
                        acc[i][j] += as_[i][c] * ks_[c][j];
        }

        float mc[4];
#pragma unroll
        for (int j = 0; j < 4; ++j) mc[j] = mcol[(size_t)b * TT + s0 + tx * 4 + j];

        float e[4][4];
        const bool diag = (ss == t_tile);
#pragma unroll
        for (int i = 0; i < 4; ++i)
#pragma unroll
            for (int j = 0; j < 4; ++j) {
                bool valid = !diag || (ty * 4 + i >= tx * 4 + j);
                e[i][j] = valid ? expf(acc[i][j] - mc[j]) : 0.f;
            }

        __syncthreads();   // everyone done reading alds (k)
#pragma unroll
        for (int i = 0; i < 4; ++i)
            *(float4*)&alds[ty * 4 + i][tx * 4] = make_float4(e[i][0], e[i][1], e[i][2], e[i][3]);
        __syncthreads();

        // GEMM2: oacc += E * V'
#pragma unroll 4
        for (int s4 = 0; s4 < 16; ++s4) {
            float es_[4][4], vs_[4][4];
#pragma unroll
            for (int i = 0; i < 4; ++i) {
                float4 ev = *(const float4*)&alds[ty * 4 + i][s4 * 4];
                es_[i][0] = ev.x; es_[i][1] = ev.y; es_[i][2] = ev.z; es_[i][3] = ev.w;
            }
#pragma unroll
            for (int c = 0; c < 4; ++c) {
                float4 vv = *(const float4*)&vlds[s4 * 4 + c][tx * 4];
                vs_[c][0] = vv.x; vs_[c][1] = vv.y; vs_[c][2] = vv.z; vs_[c][3] = vv.w;
            }
#pragma unroll
            for (int i = 0; i < 4; ++i)
#pragma unroll
                for (int j = 0; j < 4; ++j)
#pragma unroll
                    for (int c = 0; c < 4; ++c)
                        oacc[i][j] += es_[i][c] * vs_[c][j];
        }
    }

#pragma unroll
    for (int i = 0; i < 4; ++i) {
        float4 o = make_float4(oacc[i][0], oacc[i][1], oacc[i][2], oacc[i][3]);
        *(float4*)(out + ((size_t)b * TT + t0 + ty * 4 + i) * HH + tx * 4) = o;
    }
}

extern "C" void kernel_launch(void* const* d_in, const int* in_sizes, int n_in,
                              void* d_out, int out_size, void* d_ws, size_t ws_size,
                              hipStream_t stream)
{
    const float* x  = (const float*)d_in[0];
    const float* Wq = (const float*)d_in[1];
    const float* bq = (const float*)d_in[2];
    const float* Wk = (const float*)d_in[3];
    const float* bk = (const float*)d_in[4];
    const float* Wv = (const float*)d_in[5];
    const float* bv = (const float*)d_in[6];

    float* qbuf = (float*)d_ws;
    float* kbuf = qbuf + (size_t)BT * HH;
    float* vbuf = kbuf + (size_t)BT * HH;
    float* mcol = vbuf + (size_t)BT * HH;
    float* dcol = mcol + BT;

    qkv_kernel<<<dim3(BT / 64), 256, 0, stream>>>(x, Wq, bq, Wk, bk, Wv, bv,
                                                  qbuf, kbuf, vbuf);
    colstats_kernel<<<dim3(32, BB), 256, 0, stream>>>(qbuf, kbuf, mcol, dcol);
    attnout_kernel<<<dim3(32, BB), 256, 0, stream>>>(qbuf, kbuf, vbuf, mcol, dcol,
                                                     (float*)d_out);
}

// Round 3
// 359.372 us; speedup vs baseline: 2.0680x; 2.0680x over previous
//
#include <hip/hip_runtime.h>
#include <hip/hip_bf16.h>
#include <math.h>

#define TT 2048
#define NB 16

typedef short short8 __attribute__((ext_vector_type(8)));   // 8 bf16 (4 VGPR) MFMA frag
typedef float f32x4 __attribute__((ext_vector_type(4)));
typedef unsigned short us4 __attribute__((ext_vector_type(4)));

#define MFMA16(a,b,c) __builtin_amdgcn_mfma_f32_16x16x32_bf16((a),(b),(c),0,0,0)

typedef const __attribute__((address_space(1))) unsigned gas_u32;
typedef __attribute__((address_space(3))) unsigned las_u32;

__device__ __forceinline__ void gll16(const void* g, void* l) {
    // global->LDS direct copy, 16B per lane; dest = wave-uniform base + lane*16
    __builtin_amdgcn_global_load_lds((gas_u32*)g, (las_u32*)l, 16, 0, 0);
}

__device__ __forceinline__ unsigned short bf16rn(float f) {
    unsigned u = __float_as_uint(f);
    u += 0x7FFFu + ((u >> 16) & 1u);        // round-to-nearest-even
    return (unsigned short)(u >> 16);
}
__device__ __forceinline__ float bf16tof(unsigned short h) {
    return __uint_as_float(((unsigned)h) << 16);
}

// ---------------------------------------------------------------------------
// Kernel 0: W prep.  W[k][n] fp32 -> WT[m][part][n][1024 k] bf16 hi/lo.
// Wq additionally scaled by log2(e) so softmax uses exp2 directly.
// ---------------------------------------------------------------------------
__global__ void wprep_kernel(const float* __restrict__ Wq,
                             const float* __restrict__ Wk,
                             const float* __restrict__ Wv,
                             short* __restrict__ WT)
{
    const int m = blockIdx.x >> 6, n = blockIdx.x & 63, tid = threadIdx.x;
    const float* W = (m == 0) ? Wq : ((m == 1) ? Wk : Wv);
    const float sc = (m == 0) ? 1.4426950408889634f : 1.f;
    const int k0 = tid * 4;
    us4 hv, lv;
#pragma unroll
    for (int r = 0; r < 4; ++r) {
        float v = W[(size_t)(k0 + r) * 64 + n] * sc;
        unsigned short hh = bf16rn(v);
        hv[r] = hh;
        lv[r] = bf16rn(v - bf16tof(hh));
    }
    *(us4*)&WT[((size_t)(m * 2 + 0) * 64 + n) * 1024 + k0] = hv;
    *(us4*)&WT[((size_t)(m * 2 + 1) * 64 + n) * 1024 + k0] = lv;
}

// ---------------------------------------------------------------------------
// Kernel 1: QKV.  128 rows/block, 4 waves (wave = 32 rows), N=192, K chunk 64.
// q,k computed SWAPPED (D[n][t] = Wt x^T) -> packed b64 hi/lo stores to
// qhl/khl[b][t][part][64].  v computed normal (D[t][d]) -> vT[b][d][t] bf16.
// LDS frag layout: [part][kk][row][g8][8] (16B units at 64B row stride).
// ---------------------------------------------------------------------------
__global__ __launch_bounds__(256, 2) void qkv_kernel(
    const float* __restrict__ x,
    const float* __restrict__ bq, const float* __restrict__ bk,
    const float* __restrict__ bv,
    const short* __restrict__ WT,
    short* __restrict__ qhl, short* __restrict__ khl, short* __restrict__ vT)
{
    __shared__ short xs[16384];   // [part 2][kk 2][row 128][g8 4][8]
    __shared__ short ws[24576];   // [part 2][kk 2][n 192][g8 4][8]
    const int tid = threadIdx.x;
    const int w = tid >> 6, l15 = tid & 15, g = (tid >> 4) & 3;
    const int t0 = blockIdx.x * 128;

    f32x4 acc[12][2];
    const f32x4 z = {0.f, 0.f, 0.f, 0.f};
#pragma unroll
    for (int i = 0; i < 12; ++i) { acc[i][0] = z; acc[i][1] = z; }

#pragma unroll 1
    for (int kc = 0; kc < 16; ++kc) {
        // stage W (3072 16B units, pure global_load_lds)
#pragma unroll
        for (int p = 0; p < 12; ++p) {
            int u = tid + p * 256;
            int part = u / 1536; int r = u - part * 1536;
            int kk = r / 768;    int r2 = r - kk * 768;
            int n = r2 >> 2, g8 = r2 & 3;
            int m = n >> 6, nn = n & 63;
            const short* src = WT + (((size_t)((m * 2 + part) * 64 + nn)) << 10)
                                  + kc * 64 + kk * 32 + g8 * 8;
            gll16(src, &ws[((tid & ~63) + p * 256) * 8]);
        }
        // stage x with fp32 -> bf16 hi/lo conversion (1024 8-elem groups)
#pragma unroll
        for (int p = 0; p < 4; ++p) {
            int idx = tid + p * 256;
            int kk = idx >> 9; int rem = idx & 511;
            int row = rem >> 2, g8 = rem & 3;
            const float* xp = x + (size_t)(t0 + row) * 1024 + kc * 64 + kk * 32 + g8 * 8;
            f32x4 a = *(const f32x4*)xp;
            f32x4 b2 = *(const f32x4*)(xp + 4);
            short8 h8, l8;
#pragma unroll
            for (int j = 0; j < 4; ++j) {
                unsigned short hh = bf16rn(a[j]);
                h8[j] = (short)hh; l8[j] = (short)bf16rn(a[j] - bf16tof(hh));
                hh = bf16rn(b2[j]);
                h8[j + 4] = (short)hh; l8[j + 4] = (short)bf16rn(b2[j] - bf16tof(hh));
            }
            *(short8*)&xs[((kk * 128 + row) * 4 + g8) * 8] = h8;             // part 0
            *(short8*)&xs[(((2 + kk) * 128 + row) * 4 + g8) * 8] = l8;       // part 1
        }
        __syncthreads();

#pragma unroll
        for (int kk = 0; kk < 2; ++kk) {
            short8 xf[2][2];
#pragma unroll
            for (int m2 = 0; m2 < 2; ++m2)
#pragma unroll
                for (int part = 0; part < 2; ++part)
                    xf[m2][part] = *(const short8*)
                        &xs[(((part * 2 + kk) * 128 + (w * 32 + m2 * 16 + l15)) * 4 + g) * 8];
#pragma unroll
            for (int Nb = 0; Nb < 12; ++Nb) {
                short8 wh = *(const short8*)&ws[(((kk) * 192 + Nb * 16 + l15) * 4 + g) * 8];
                short8 wl = *(const short8*)&ws[(((2 + kk) * 192 + Nb * 16 + l15) * 4 + g) * 8];
#pragma unroll
                for (int m2 = 0; m2 < 2; ++m2) {
                    if (Nb < 8) {    // q,k: swapped, A = W^T frag, B = x frag
                        acc[Nb][m2] = MFMA16(wh, xf[m2][0], acc[Nb][m2]);
                        acc[Nb][m2] = MFMA16(wh, xf[m2][1], acc[Nb][m2]);
                        acc[Nb][m2] = MFMA16(wl, xf[m2][0], acc[Nb][m2]);
                    } else {         // v: normal, A = x frag, B = W^T frag
                        acc[Nb][m2] = MFMA16(xf[m2][0], wh, acc[Nb][m2]);
                        acc[Nb][m2] = MFMA16(xf[m2][1], wh, acc[Nb][m2]);
                        acc[Nb][m2] = MFMA16(xf[m2][0], wl, acc[Nb][m2]);
                    }
                }
            }
        }
        __syncthreads();
    }

    const float LOG2E = 1.4426950408889634f;
#pragma unroll
    for (int Nb = 0; Nb < 12; ++Nb) {
#pragma unroll
        for (int m2 = 0; m2 < 2; ++m2) {
            f32x4 a = acc[Nb][m2];
            if (Nb < 8) {
                // D[n][t]: n = Nb*16 + g*4 + r, t = t0 + w*32 + m2*16 + l15
                const bool isq = (Nb < 4);
                const int nbase = (Nb & 3) * 16 + g * 4;
                const int trow = t0 + w * 32 + m2 * 16 + l15;
                const float* bias = isq ? bq : bk;
                us4 hv, lv;
#pragma unroll
                for (int r = 0; r < 4; ++r) {
                    float v = a[r] + (isq ? bias[nbase + r] * LOG2E : bias[nbase + r]);
                    unsigned short hh = bf16rn(v);
                    hv[r] = hh; lv[r] = bf16rn(v - bf16tof(hh));
                }
                short* dst = (isq ? qhl : khl) + ((size_t)trow * 2) * 64 + nbase;
                *(us4*)dst = hv;
                *(us4*)(dst + 64) = lv;
            } else {
                // D[t][d]: t = t0 + w*32 + m2*16 + g*4 + r, d = (Nb-8)*16 + l15
                const int d = (Nb - 8) * 16 + l15;
                const int tbase = t0 + w * 32 + m2 * 16 + g * 4;
                const float bvd = bv[d];
                us4 pk;
#pragma unroll
                for (int r = 0; r < 4; ++r) pk[r] = bf16rn(a[r] + bvd);
                const int b = tbase >> 11, ttl = tbase & 2047;
                *(us4*)&vT[((size_t)(b * 64 + d)) * 2048 + ttl] = pk;
            }
        }
    }
}

// ---------------------------------------------------------------------------
// Kernel 2: column stats.  Block = (sblk, b), 64 columns s.  S'^T tiles via
// mfma(A=k, B=q).  m fixed from diagonal tile (clamped >= 0) -> single exp2
// per element.  Output c[s] = m + log2(D).
// ---------------------------------------------------------------------------
__global__ __launch_bounds__(256, 2) void colstats_kernel(
    const short* __restrict__ qhl, const short* __restrict__ khl,
    float* __restrict__ ccol)
{
    __shared__ short kb[8192];   // [part][kk][row 64][g8][8]
    __shared__ short qb[8192];
    const int tid = threadIdx.x;
    const int w = tid >> 6, l15 = tid & 15, g = (tid >> 4) & 3;
    const int sblk = blockIdx.x, b = blockIdx.y;
    const int s0 = sblk * 64;

#pragma unroll
    for (int p = 0; p < 4; ++p) {
        int u = tid + p * 256;
        int part = u >> 9, kk = (u >> 8) & 1, row = (u >> 2) & 63, g8 = u & 3;
        const short* src = khl + ((size_t)(b * TT + s0 + row) * 2 + part) * 64
                               + kk * 32 + g8 * 8;
        gll16(src, &kb[((tid & ~63) + p * 256) * 8]);
    }

    short8 kf[2][2];
    float m_slot[4], d_slot[4];
    const f32x4 z = {0.f, 0.f, 0.f, 0.f};

#pragma unroll 1
    for (int tt = sblk; tt < 32; ++tt) {
#pragma unroll
        for (int p = 0; p < 4; ++p) {
            int u = tid + p * 256;
            int part = u >> 9, kk = (u >> 8) & 1, row = (u >> 2) & 63, g8 = u & 3;
            const short* src = qhl + ((size_t)(b * TT + tt * 64 + row) * 2 + part) * 64
                                   + kk * 32 + g8 * 8;
            gll16(src, &qb[((tid & ~63) + p * 256) * 8]);
        }
        __syncthreads();
        if (tt == sblk) {
#pragma unroll
            for (int kk = 0; kk < 2; ++kk)
#pragma unroll
                for (int part = 0; part < 2; ++part)
                    kf[kk][part] = *(const short8*)
                        &kb[(((part * 2 + kk) * 64 + w * 16 + l15) * 4 + g) * 8];
        }
        f32x4 a4[4];
#pragma unroll
        for (int tb = 0; tb < 4; ++tb) {
            a4[tb] = z;
#pragma unroll
            for (int kk = 0; kk < 2; ++kk) {
                short8 qh = *(const short8*)&qb[(((kk) * 64 + tb * 16 + l15) * 4 + g) * 8];
                short8 ql = *(const short8*)&qb[(((2 + kk) * 64 + tb * 16 + l15) * 4 + g) * 8];
                a4[tb] = MFMA16(kf[kk][0], qh, a4[tb]);
                a4[tb] = MFMA16(kf[kk][0], ql, a4[tb]);
                a4[tb] = MFMA16(kf[kk][1], qh, a4[tb]);
            }
        }
        // lane element: s_local = w*16 + g*4 + r, t_local = tb*16 + l15
        if (tt == sblk) {
#pragma unroll
            for (int tb = 0; tb < 4; ++tb)
#pragma unroll
                for (int r = 0; r < 4; ++r)
                    if (tb * 16 + l15 < w * 16 + g * 4 + r) a4[tb][r] = -INFINITY;
#pragma unroll
            for (int r = 0; r < 4; ++r) {
                float mx = fmaxf(fmaxf(a4[0][r], a4[1][r]), fmaxf(a4[2][r], a4[3][r]));
                mx = fmaxf(mx, __shfl_xor(mx, 1));
                mx = fmaxf(mx, __shfl_xor(mx, 2));
                mx = fmaxf(mx, __shfl_xor(mx, 4));
                mx = fmaxf(mx, __shfl_xor(mx, 8));
                m_slot[r] = fmaxf(mx, 0.f);
                d_slot[r] = exp2f(a4[0][r] - m_slot[r]) + exp2f(a4[1][r] - m_slot[r])
                          + exp2f(a4[2][r] - m_slot[r]) + exp2f(a4[3][r] - m_slot[r]);
            }
        } else {
#pragma unroll
            for (int r = 0; r < 4; ++r)
                d_slot[r] += exp2f(a4[0][r] - m_slot[r]) + exp2f(a4[1][r] - m_slot[r])
                           + exp2f(a4[2][r] - m_slot[r]) + exp2f(a4[3][r] - m_slot[r]);
        }
        __syncthreads();
    }
#pragma unroll
    for (int r = 0; r < 4; ++r) {
        float dv = d_slot[r];
        dv += __shfl_xor(dv, 1); dv += __shfl_xor(dv, 2);
        dv += __shfl_xor(dv, 4); dv += __shfl_xor(dv, 8);
        d_slot[r] = dv;
    }
    if (l15 == 0) {
        f32x4 c;
#pragma unroll
        for (int r = 0; r < 4; ++r) c[r] = m_slot[r] + log2f(d_slot[r]);
        *(f32x4*)&ccol[(size_t)b * TT + s0 + w * 16 + g * 4] = c;
    }
}

// ---------------------------------------------------------------------------
// Kernel 3: output.  Block = (tblk, b), 64 rows t.  Per s-tile:
// S'^T = mfma(k, q) (q frags in regs from global), e' = exp2(S'-c[s]) -> bf16
// to LDS, then O^T += mfma(V^T, E^T).  Final store float4 along d.
// ---------------------------------------------------------------------------
__global__ __launch_bounds__(256, 2) void attnout_kernel(
    const short* __restrict__ qhl, const short* __restrict__ khl,
    const short* __restrict__ vT, const float* __restrict__ ccol,
    float* __restrict__ out)
{
    __shared__ short kb[8192];   // [part][kk][row 64][g8][8]
    __shared__ short vb[4096];   // [kgs 2][d 64][g8][8]
    __shared__ short eb[4096];   // [kgs 2][t 64][g8][8]
    __shared__ float cb[64];
    const int tid = threadIdx.x;
    const int w = tid >> 6, l15 = tid & 15, g = (tid >> 4) & 3;
    const int tblk = blockIdx.x, b = blockIdx.y;
    const int t0 = tblk * 64;

    short8 qf[4][2][2];
#pragma unroll
    for (int tb = 0; tb < 4; ++tb)
#pragma unroll
        for (int kk = 0; kk < 2; ++kk)
#pragma unroll
            for (int part = 0; part < 2; ++part)
                qf[tb][kk][part] = *(const short8*)
                    (qhl + ((size_t)(b * TT + t0 + tb * 16 + l15) * 2 + part) * 64
                         + kk * 32 + g * 8);

    f32x4 oacc[4];
    const f32x4 z = {0.f, 0.f, 0.f, 0.f};
#pragma unroll
    for (int tb = 0; tb < 4; ++tb) oacc[tb] = z;

#pragma unroll 1
    for (int ss = 0; ss <= tblk; ++ss) {
        const int s0 = ss * 64;
#pragma unroll
        for (int p = 0; p < 4; ++p) {
            int u = tid + p * 256;
            int part = u >> 9, kk = (u >> 8) & 1, row = (u >> 2) & 63, g8 = u & 3;
            gll16(khl + ((size_t)(b * TT + s0 + row) * 2 + part) * 64 + kk * 32 + g8 * 8,
                  &kb[((tid & ~63) + p * 256) * 8]);
        }
#pragma unroll
        for (int p = 0; p < 2; ++p) {
            int u = tid + p * 256;
            int kgs = u >> 8, d = (u >> 2) & 63, g8 = u & 3;
            gll16(vT + ((size_t)(b * 64 + d)) * 2048 + s0 + kgs * 32 + g8 * 8,
                  &vb[((tid & ~63) + p * 256) * 8]);
        }
        if (tid < 64) cb[tid] = ccol[(size_t)b * TT + s0 + tid];
        __syncthreads();

        short8 kf2[2][2];
#pragma unroll
        for (int kk = 0; kk < 2; ++kk)
#pragma unroll
            for (int part = 0; part < 2; ++part)
                kf2[kk][part] = *(const short8*)
                    &kb[(((part * 2 + kk) * 64 + w * 16 + l15) * 4 + g) * 8];

        f32x4 a4[4];
#pragma unroll
        for (int tb = 0; tb < 4; ++tb) {
            a4[tb] = z;
#pragma unroll
            for (int kk = 0; kk < 2; ++kk) {
                a4[tb] = MFMA16(kf2[kk][0], qf[tb][kk][0], a4[tb]);
                a4[tb] = MFMA16(kf2[kk][0], qf[tb][kk][1], a4[tb]);
                a4[tb] = MFMA16(kf2[kk][1], qf[tb][kk][0], a4[tb]);
            }
        }
        const f32x4 c4 = *(const f32x4*)&cb[w * 16 + g * 4];
        const bool diag = (ss == tblk);
#pragma unroll
        for (int tb = 0; tb < 4; ++tb) {
            us4 pk;
#pragma unroll
            for (int r = 0; r < 4; ++r) {
                float e = exp2f(a4[tb][r] - c4[r]);
                if (diag && (tb * 16 + l15 < w * 16 + g * 4 + r)) e = 0.f;
                pk[r] = bf16rn(e);
            }
            const int kgs = w >> 1, g8s = (w & 1) * 2 + (g >> 1), j0 = (g & 1) * 4;
            *(us4*)&eb[((kgs * 64 + tb * 16 + l15) * 4 + g8s) * 8 + j0] = pk;
        }
        __syncthreads();

        short8 vf[2];
#pragma unroll
        for (int kgs = 0; kgs < 2; ++kgs)
            vf[kgs] = *(const short8*)&vb[(((kgs * 64 + w * 16 + l15) * 4 + g) * 8)];
#pragma unroll
        for (int tb = 0; tb < 4; ++tb)
#pragma unroll
            for (int kgs = 0; kgs < 2; ++kgs) {
                short8 ef = *(const short8*)&eb[(((kgs * 64 + tb * 16 + l15) * 4 + g) * 8)];
                oacc[tb] = MFMA16(vf[kgs], ef, oacc[tb]);
            }
        __syncthreads();
    }
    // O^T D-frag: col j = t = l15, row i = d = w*16 + g*4 + r -> float4 along d
#pragma unroll
    for (int tb = 0; tb < 4; ++tb) {
        const int t = t0 + tb * 16 + l15;
        const int d0 = w * 16 + g * 4;
        *(f32x4*)(out + ((size_t)(b * TT + t)) * 64 + d0) = oacc[tb];
    }
}

extern "C" void kernel_launch(void* const* d_in, const int* in_sizes, int n_in,
                              void* d_out, int out_size, void* d_ws, size_t ws_size,
                              hipStream_t stream)
{
    const float* x  = (const float*)d_in[0];
    const float* Wq = (const float*)d_in[1];
    const float* bq = (const float*)d_in[2];
    const float* Wk = (const float*)d_in[3];
    const float* bk = (const float*)d_in[4];
    const float* Wv = (const float*)d_in[5];
    const float* bv = (const float*)d_in[6];

    char* wsb = (char*)d_ws;
    short* qhl = (short*)wsb;                        // 8,388,608 B
    short* khl = (short*)(wsb + 8388608);            // 8,388,608 B
    short* vTb = (short*)(wsb + 16777216);           // 4,194,304 B
    short* WT  = (short*)(wsb + 20971520);           //   786,432 B
    float* ccol = (float*)(wsb + 21757952);          //   131,072 B  (total ~21.9 MB)

    wprep_kernel<<<dim3(192), 256, 0, stream>>>(Wq, Wk, Wv, WT);
    qkv_kernel<<<dim3(256), 256, 0, stream>>>(x, bq, bk, bv, WT, qhl, khl, vTb);
    colstats_kernel<<<dim3(32, NB), 256, 0, stream>>>(qhl, khl, ccol);
    attnout_kernel<<<dim3(32, NB), 256, 0, stream>>>(qhl, khl, vTb, ccol, (float*)d_out);
}

// Round 5
// 310.262 us; speedup vs baseline: 2.3954x; 1.1583x over previous
//
#include <hip/hip_runtime.h>
#include <hip/hip_bf16.h>
#include <math.h>

#define TT 2048
#define NB 16

typedef short short8 __attribute__((ext_vector_type(8)));   // 8 bf16 (4 VGPR) MFMA frag
typedef float f32x4 __attribute__((ext_vector_type(4)));
typedef unsigned short us4 __attribute__((ext_vector_type(4)));

#define MFMA16(a,b,c) __builtin_amdgcn_mfma_f32_16x16x32_bf16((a),(b),(c),0,0,0)

typedef const __attribute__((address_space(1))) unsigned gas_u32;
typedef __attribute__((address_space(3))) unsigned las_u32;

__device__ __forceinline__ void gll16(const void* g, void* l) {
    // global->LDS direct copy, 16B per lane; dest = wave-uniform base + lane*16
    __builtin_amdgcn_global_load_lds((gas_u32*)g, (las_u32*)l, 16, 0, 0);
}

__device__ __forceinline__ unsigned short bf16rn(float f) {
    unsigned u = __float_as_uint(f);
    u += 0x7FFFu + ((u >> 16) & 1u);        // round-to-nearest-even
    return (unsigned short)(u >> 16);
}
__device__ __forceinline__ float bf16tof(unsigned short h) {
    return __uint_as_float(((unsigned)h) << 16);
}

// ---------------------------------------------------------------------------
// Kernel 0: W prep.  W[k][n] fp32 -> WT[m][part][n][1024 k] bf16 hi/lo.
// Wq additionally scaled by log2(e) so softmax uses exp2 directly.
// ---------------------------------------------------------------------------
__global__ void wprep_kernel(const float* __restrict__ Wq,
                             const float* __restrict__ Wk,
                             const float* __restrict__ Wv,
                             short* __restrict__ WT)
{
    const int m = blockIdx.x >> 6, n = blockIdx.x & 63, tid = threadIdx.x;
    const float* W = (m == 0) ? Wq : ((m == 1) ? Wk : Wv);
    const float sc = (m == 0) ? 1.4426950408889634f : 1.f;
    const int k0 = tid * 4;
    us4 hv, lv;
#pragma unroll
    for (int r = 0; r < 4; ++r) {
        float v = W[(size_t)(k0 + r) * 64 + n] * sc;
        unsigned short hh = bf16rn(v);
        hv[r] = hh;
        lv[r] = bf16rn(v - bf16tof(hh));
    }
    *(us4*)&WT[((size_t)(m * 2 + 0) * 64 + n) * 1024 + k0] = hv;
    *(us4*)&WT[((size_t)(m * 2 + 1) * 64 + n) * 1024 + k0] = lv;
}

// ---------------------------------------------------------------------------
// zero dcol (ws is re-poisoned to 0xAA before every timed launch)
// ---------------------------------------------------------------------------
__global__ void zero_kernel(float* __restrict__ p) {
    p[blockIdx.x * 256 + threadIdx.x] = 0.f;
}

// ---------------------------------------------------------------------------
// Kernel 1: QKV.  64 rows/block (grid 512 -> 2 blocks/CU), 4 waves of 16 rows.
// q,k SWAPPED (D[n][t] = Wt x^T), 3-pass hi/lo -> qhl/khl[b][t][part][64].
// v normal (D[t][d]), single hi pass -> vT[b][d][t] bf16.
// ---------------------------------------------------------------------------
__global__ __launch_bounds__(256, 2) void qkv_kernel(
    const float* __restrict__ x,
    const float* __restrict__ bq, const float* __restrict__ bk,
    const float* __restrict__ bv,
    const short* __restrict__ WT,
    short* __restrict__ qhl, short* __restrict__ khl, short* __restrict__ vT)
{
    __shared__ short xs[8192];    // [part 2][kk 2][row 64][g8 4][8]
    __shared__ short ws[24576];   // [part 2][kk 2][n 192][g8 4][8]
    const int tid = threadIdx.x;
    const int w = tid >> 6, l15 = tid & 15, g = (tid >> 4) & 3;
    const int t0 = blockIdx.x * 64;

    f32x4 acc[12];
    const f32x4 z = {0.f, 0.f, 0.f, 0.f};
#pragma unroll
    for (int i = 0; i < 12; ++i) acc[i] = z;

#pragma unroll 1
    for (int kc = 0; kc < 16; ++kc) {
        // stage W (3072 16B units via global_load_lds)
#pragma unroll
        for (int p = 0; p < 12; ++p) {
            int u = tid + p * 256;
            int part = u / 1536; int r = u - part * 1536;
            int kk = r / 768;    int r2 = r - kk * 768;
            int n = r2 >> 2, g8 = r2 & 3;
            int m = n >> 6, nn = n & 63;
            const short* src = WT + (((size_t)((m * 2 + part) * 64 + nn)) << 10)
                                  + kc * 64 + kk * 32 + g8 * 8;
            gll16(src, &ws[((tid & ~63) + p * 256) * 8]);
        }
        // stage x with fp32 -> bf16 hi/lo conversion (512 8-elem groups)
#pragma unroll
        for (int p = 0; p < 2; ++p) {
            int idx = tid + p * 256;
            int kk = idx >> 8; int rem = idx & 255;
            int row = rem >> 2, g8 = rem & 3;
            const float* xp = x + (size_t)(t0 + row) * 1024 + kc * 64 + kk * 32 + g8 * 8;
            f32x4 a = *(const f32x4*)xp;
            f32x4 b2 = *(const f32x4*)(xp + 4);
            short8 h8, l8;
#pragma unroll
            for (int j = 0; j < 4; ++j) {
                unsigned short hh = bf16rn(a[j]);
                h8[j] = (short)hh; l8[j] = (short)bf16rn(a[j] - bf16tof(hh));
                hh = bf16rn(b2[j]);
                h8[j + 4] = (short)hh; l8[j + 4] = (short)bf16rn(b2[j] - bf16tof(hh));
            }
            *(short8*)&xs[((kk * 64 + row) * 4 + g8) * 8] = h8;              // part 0
            *(short8*)&xs[(((2 + kk) * 64 + row) * 4 + g8) * 8] = l8;        // part 1
        }
        __syncthreads();

#pragma unroll
        for (int kk = 0; kk < 2; ++kk) {
            short8 xf[2];
#pragma unroll
            for (int part = 0; part < 2; ++part)
                xf[part] = *(const short8*)
                    &xs[(((part * 2 + kk) * 64 + w * 16 + l15) * 4 + g) * 8];
#pragma unroll
            for (int Nb = 0; Nb < 12; ++Nb) {
                short8 wh = *(const short8*)&ws[((kk * 192 + Nb * 16 + l15) * 4 + g) * 8];
                if (Nb < 8) {    // q,k: swapped, 3-pass hi/lo
                    short8 wl = *(const short8*)
                        &ws[(((2 + kk) * 192 + Nb * 16 + l15) * 4 + g) * 8];
                    acc[Nb] = MFMA16(wh, xf[0], acc[Nb]);
                    acc[Nb] = MFMA16(wh, xf[1], acc[Nb]);
                    acc[Nb] = MFMA16(wl, xf[0], acc[Nb]);
                } else {         // v: normal, single hi pass (vT is bf16 anyway)
                    acc[Nb] = MFMA16(xf[0], wh, acc[Nb]);
                }
            }
        }
        __syncthreads();
    }

    const float LOG2E = 1.4426950408889634f;
#pragma unroll
    for (int Nb = 0; Nb < 12; ++Nb) {
        f32x4 a = acc[Nb];
        if (Nb < 8) {
            // D[n][t]: n = Nb*16 + g*4 + r, t = t0 + w*16 + l15
            const bool isq = (Nb < 4);
            const int nbase = (Nb & 3) * 16 + g * 4;
            const int trow = t0 + w * 16 + l15;
            const float* bias = isq ? bq : bk;
            us4 hv, lv;
#pragma unroll
            for (int r = 0; r < 4; ++r) {
                float v = a[r] + (isq ? bias[nbase + r] * LOG2E : bias[nbase + r]);
                unsigned short hh = bf16rn(v);
                hv[r] = hh; lv[r] = bf16rn(v - bf16tof(hh));
            }
            short* dst = (isq ? qhl : khl) + ((size_t)trow * 2) * 64 + nbase;
            *(us4*)dst = hv;
            *(us4*)(dst + 64) = lv;
        } else {
            // D[t][d]: t = t0 + w*16 + g*4 + r, d = (Nb-8)*16 + l15
            const int d = (Nb - 8) * 16 + l15;
            const int tbase = t0 + w * 16 + g * 4;
            const float bvd = bv[d];
            us4 pk;
#pragma unroll
            for (int r = 0; r < 4; ++r) pk[r] = bf16rn(a[r] + bvd);
            const int b = tbase >> 11, ttl = tbase & 2047;
            *(us4*)&vT[((size_t)(b * 64 + d)) * 2048 + ttl] = pk;
        }
    }
}

// ---------------------------------------------------------------------------
// Kernel 2: column sums D[s] = sum_{t>=s} 2^{S'[t,s]}  (fixed reference m=0;
// overflow-safe since max S' ~ 66 -> D <= 2^77 << fp32 max).
// Grid (32 sblk, 4 tchunk, 16 b); each block: <= 8 q-tiles, partial D via
// fp32 atomicAdd.  attnout computes c = log2(D) on load.
// ---------------------------------------------------------------------------
__global__ __launch_bounds__(256, 4) void colstats_kernel(
    const short* __restrict__ qhl, const short* __restrict__ khl,
    float* __restrict__ dcol)
{
    __shared__ short kb[8192];   // [part 2][kk 2][row 64][g8][8]
    __shared__ short qb[8192];
    const int tid = threadIdx.x;
    const int w = tid >> 6, l15 = tid & 15, g = (tid >> 4) & 3;
    const int sblk = blockIdx.x, tc = blockIdx.y, b = blockIdx.z;
    const int tt0 = max(sblk, tc * 8), tt1 = min(32, tc * 8 + 8);
    if (tt0 >= tt1) return;
    const int s0 = sblk * 64;
    const int sl = w * 16 + g * 4;

#pragma unroll
    for (int p = 0; p < 4; ++p) {
        int u = tid + p * 256;
        int part = u >> 9, kk = (u >> 8) & 1, row = (u >> 2) & 63, g8 = u & 3;
        gll16(khl + ((size_t)(b * TT + s0 + row) * 2 + part) * 64 + kk * 32 + g8 * 8,
              &kb[((tid & ~63) + p * 256) * 8]);
    }

    short8 kf[2][2];
    float dsl[4] = {0.f, 0.f, 0.f, 0.f};
    const f32x4 z = {0.f, 0.f, 0.f, 0.f};

#pragma unroll 1
    for (int tt = tt0; tt < tt1; ++tt) {
#pragma unroll
        for (int p = 0; p < 4; ++p) {
            int u = tid + p * 256;
            int part = u >> 9, kk = (u >> 8) & 1, row = (u >> 2) & 63, g8 = u & 3;
            gll16(qhl + ((size_t)(b * TT + tt * 64 + row) * 2 + part) * 64 + kk * 32 + g8 * 8,
                  &qb[((tid & ~63) + p * 256) * 8]);
        }
        __syncthreads();
        if (tt == tt0) {
#pragma unroll
            for (int kk = 0; kk < 2; ++kk)
#pragma unroll
                for (int part = 0; part < 2; ++part)
                    kf[kk][part] = *(const short8*)
                        &kb[(((part * 2 + kk) * 64 + w * 16 + l15) * 4 + g) * 8];
        }
#pragma unroll
        for (int tb = 0; tb < 4; ++tb) {
            f32x4 a = z;
#pragma unroll
            for (int kk = 0; kk < 2; ++kk) {
                short8 qh = *(const short8*)&qb[((kk * 64 + tb * 16 + l15) * 4 + g) * 8];
                short8 ql = *(const short8*)&qb[(((2 + kk) * 64 + tb * 16 + l15) * 4 + g) * 8];
                a = MFMA16(kf[kk][0], qh, a);
                a = MFMA16(kf[kk][0], ql, a);
                a = MFMA16(kf[kk][1], qh, a);
            }
            if (tt == sblk) {   // diagonal tile: t_local < s_local -> masked
#pragma unroll
                for (int r = 0; r < 4; ++r)
                    if (tb * 16 + l15 < sl + r) a[r] = -INFINITY;
            }
#pragma unroll
            for (int r = 0; r < 4; ++r) dsl[r] += exp2f(a[r]);
        }
        __syncthreads();
    }
#pragma unroll
    for (int r = 0; r < 4; ++r) {
        float dv = dsl[r];
        dv += __shfl_xor(dv, 1); dv += __shfl_xor(dv, 2);
        dv += __shfl_xor(dv, 4); dv += __shfl_xor(dv, 8);
        dsl[r] = dv;
    }
    if (l15 == 0) {
#pragma unroll
        for (int r = 0; r < 4; ++r)
            atomicAdd(&dcol[(size_t)b * TT + s0 + sl + r], dsl[r]);
    }
}

// ---------------------------------------------------------------------------
// Kernel 3: output, strip-paired for uniform load.  Block (p, b) owns 32-row
// t-strips iA=p and iB=63-p (work = const ~33 strip-tiles); each staged
// k/v s-tile is shared by both strips.  O^T += mfma(V^T, E^T).
// ---------------------------------------------------------------------------
__global__ __launch_bounds__(256, 2) void attnout_kernel(
    const short* __restrict__ qhl, const short* __restrict__ khl,
    const short* __restrict__ vT, const float* __restrict__ dcol,
    float* __restrict__ out)
{
    __shared__ short kb[8192];    // [part 2][kk 2][s 64][g8][8]
    __shared__ short vb[4096];    // [kgs 2][d 64][g8][8]
    __shared__ short ebA[2048];   // [kgs 2][t 32][g8][8]
    __shared__ short ebB[2048];
    __shared__ float cb[64];
    const int tid = threadIdx.x;
    const int w = tid >> 6, l15 = tid & 15, g = (tid >> 4) & 3;
    const int p = blockIdx.x, b = blockIdx.y;
    const int iA = p, iB = 63 - p;
    const int nA = iA >> 1, nB = iB >> 1;
    const int sl = w * 16 + g * 4;

    short8 qfA[2][2][2], qfB[2][2][2];
#pragma unroll
    for (int tb = 0; tb < 2; ++tb)
#pragma unroll
        for (int kk = 0; kk < 2; ++kk)
#pragma unroll
            for (int part = 0; part < 2; ++part) {
                qfA[tb][kk][part] = *(const short8*)
                    (qhl + ((size_t)(b * TT + iA * 32 + tb * 16 + l15) * 2 + part) * 64
                         + kk * 32 + g * 8);
                qfB[tb][kk][part] = *(const short8*)
                    (qhl + ((size_t)(b * TT + iB * 32 + tb * 16 + l15) * 2 + part) * 64
                         + kk * 32 + g * 8);
            }

    f32x4 oaccA[2], oaccB[2];
    const f32x4 z = {0.f, 0.f, 0.f, 0.f};
    oaccA[0] = z; oaccA[1] = z; oaccB[0] = z; oaccB[1] = z;

#pragma unroll 1
    for (int ss = 0; ss <= nB; ++ss) {
        const int s0 = ss * 64;
#pragma unroll
        for (int pp = 0; pp < 4; ++pp) {
            int u = tid + pp * 256;
            int part = u >> 9, kk = (u >> 8) & 1, row = (u >> 2) & 63, g8 = u & 3;
            gll16(khl + ((size_t)(b * TT + s0 + row) * 2 + part) * 64 + kk * 32 + g8 * 8,
                  &kb[((tid & ~63) + pp * 256) * 8]);
        }
#pragma unroll
        for (int pp = 0; pp < 2; ++pp) {
            int u = tid + pp * 256;
            int kgs = u >> 8, d = (u >> 2) & 63, g8 = u & 3;
            gll16(vT + ((size_t)(b * 64 + d)) * 2048 + s0 + kgs * 32 + g8 * 8,
                  &vb[((tid & ~63) + pp * 256) * 8]);
        }
        if (tid < 64) cb[tid] = log2f(dcol[(size_t)b * TT + s0 + tid]);
        __syncthreads();

        short8 kf[2][2];
#pragma unroll
        for (int kk = 0; kk < 2; ++kk)
#pragma unroll
            for (int part = 0; part < 2; ++part)
                kf[kk][part] = *(const short8*)
                    &kb[(((part * 2 + kk) * 64 + w * 16 + l15) * 4 + g) * 8];

        const f32x4 c4 = *(const f32x4*)&cb[sl];
        const bool actA = (ss <= nA);
        const int kgs = w >> 1, g8s = (w & 1) * 2 + (g >> 1), j0 = (g & 1) * 4;

        // strip B (always active)
#pragma unroll
        for (int tb = 0; tb < 2; ++tb) {
            f32x4 a = z;
#pragma unroll
            for (int kk = 0; kk < 2; ++kk) {
                a = MFMA16(kf[kk][0], qfB[tb][kk][0], a);
                a = MFMA16(kf[kk][0], qfB[tb][kk][1], a);
                a = MFMA16(kf[kk][1], qfB[tb][kk][0], a);
            }
            const int tg = iB * 32 + tb * 16 + l15;
            us4 pk;
#pragma unroll
            for (int r = 0; r < 4; ++r) {
                float e = (s0 + sl + r <= tg) ? exp2f(a[r] - c4[r]) : 0.f;
                pk[r] = bf16rn(e);
            }
            *(us4*)&ebB[((kgs * 32 + tb * 16 + l15) * 4 + g8s) * 8 + j0] = pk;
        }
        if (actA) {
#pragma unroll
            for (int tb = 0; tb < 2; ++tb) {
                f32x4 a = z;
#pragma unroll
                for (int kk = 0; kk < 2; ++kk) {
                    a = MFMA16(kf[kk][0], qfA[tb][kk][0], a);
                    a = MFMA16(kf[kk][0], qfA[tb][kk][1], a);
                    a = MFMA16(kf[kk][1], qfA[tb][kk][0], a);
                }
                const int tg = iA * 32 + tb * 16 + l15;
                us4 pk;
#pragma unroll
                for (int r = 0; r < 4; ++r) {
                    float e = (s0 + sl + r <= tg) ? exp2f(a[r] - c4[r]) : 0.f;
                    pk[r] = bf16rn(e);
                }
                *(us4*)&ebA[((kgs * 32 + tb * 16 + l15) * 4 + g8s) * 8 + j0] = pk;
            }
        }
        __syncthreads();

        short8 vf[2];
#pragma unroll
        for (int kg = 0; kg < 2; ++kg)
            vf[kg] = *(const short8*)&vb[((kg * 64 + w * 16 + l15) * 4 + g) * 8];
#pragma unroll
        for (int tb = 0; tb < 2; ++tb)
#pragma unroll
            for (int kg = 0; kg < 2; ++kg) {
                short8 ef = *(const short8*)&ebB[((kg * 32 + tb * 16 + l15) * 4 + g) * 8];
                oaccB[tb] = MFMA16(vf[kg], ef, oaccB[tb]);
            }
        if (actA) {
#pragma unroll
            for (int tb = 0; tb < 2; ++tb)
#pragma unroll
                for (int kg = 0; kg < 2; ++kg) {
                    short8 ef = *(const short8*)&ebA[((kg * 32 + tb * 16 + l15) * 4 + g) * 8];
                    oaccA[tb] = MFMA16(vf[kg], ef, oaccA[tb]);
                }
        }
        __syncthreads();
    }

    // O^T D-frag: col = t (l15), row = d = w*16 + g*4 + r -> float4 along d
#pragma unroll
    for (int tb = 0; tb < 2; ++tb) {
        const int tA = iA * 32 + tb * 16 + l15;
        const int tB = iB * 32 + tb * 16 + l15;
        *(f32x4*)(out + ((size_t)(b * TT + tA)) * 64 + sl) = oaccA[tb];
        *(f32x4*)(out + ((size_t)(b * TT + tB)) * 64 + sl) = oaccB[tb];
    }
}

extern "C" void kernel_launch(void* const* d_in, const int* in_sizes, int n_in,
                              void* d_out, int out_size, void* d_ws, size_t ws_size,
                              hipStream_t stream)
{
    const float* x  = (const float*)d_in[0];
    const float* Wq = (const float*)d_in[1];
    const float* bq = (const float*)d_in[2];
    const float* Wk = (const float*)d_in[3];
    const float* bk = (const float*)d_in[4];
    const float* Wv = (const float*)d_in[5];
    const float* bv = (const float*)d_in[6];

    char* wsb = (char*)d_ws;
    short* qhl = (short*)wsb;                        // 8,388,608 B
    short* khl = (short*)(wsb + 8388608);            // 8,388,608 B
    short* vTb = (short*)(wsb + 16777216);           // 4,194,304 B
    short* WT  = (short*)(wsb + 20971520);           //   786,432 B
    float* dcol = (float*)(wsb + 21757952);          //   131,072 B  (total ~21.9 MB)

    zero_kernel<<<dim3(128), 256, 0, stream>>>(dcol);
    wprep_kernel<<<dim3(192), 256, 0, stream>>>(Wq, Wk, Wv, WT);
    qkv_kernel<<<dim3(512), 256, 0, stream>>>(x, bq, bk, bv, WT, qhl, khl, vTb);
    colstats_kernel<<<dim3(32, 4, NB), 256, 0, stream>>>(qhl, khl, dcol);
    attnout_kernel<<<dim3(32, NB), 256, 0, stream>>>(qhl, khl, vTb, dcol, (float*)d_out);
}

// Round 6
// 295.661 us; speedup vs baseline: 2.5137x; 1.0494x over previous
//
#include <hip/hip_runtime.h>
#include <hip/hip_bf16.h>
#include <math.h>

#define TT 2048
#define NB 16

typedef short short8 __attribute__((ext_vector_type(8)));   // 8 bf16 (4 VGPR) MFMA frag
typedef float f32x4 __attribute__((ext_vector_type(4)));
typedef unsigned short us4 __attribute__((ext_vector_type(4)));

#define MFMA16(a,b,c) __builtin_amdgcn_mfma_f32_16x16x32_bf16((a),(b),(c),0,0,0)

typedef const __attribute__((address_space(1))) unsigned gas_u32;
typedef __attribute__((address_space(3))) unsigned las_u32;

__device__ __forceinline__ void gll16(const void* g, void* l) {
    // global->LDS direct copy, 16B per lane; dest = wave-uniform base + lane*16
    __builtin_amdgcn_global_load_lds((gas_u32*)g, (las_u32*)l, 16, 0, 0);
}

__device__ __forceinline__ unsigned short bf16rn(float f) {
    unsigned u = __float_as_uint(f);
    u += 0x7FFFu + ((u >> 16) & 1u);        // round-to-nearest-even
    return (unsigned short)(u >> 16);
}
__device__ __forceinline__ float bf16tof(unsigned short h) {
    return __uint_as_float(((unsigned)h) << 16);
}

// strip i (32 t-rows): number of preceding strip-tiles = h*(h+1) + (i&1)*(h+1), h=i>>1
__device__ __forceinline__ int strip_base(int i) {
    int h = i >> 1;
    return h * (h + 1) + (i & 1) * (h + 1);
}

// ---------------------------------------------------------------------------
// Kernel 0: W prep.  W[k][n] fp32 -> WT[m][part][n][1024 k] bf16 hi/lo.
// Wq additionally scaled by log2(e) so softmax uses exp2 directly.
// ---------------------------------------------------------------------------
__global__ void wprep_kernel(const float* __restrict__ Wq,
                             const float* __restrict__ Wk,
                             const float* __restrict__ Wv,
                             short* __restrict__ WT)
{
    const int m = blockIdx.x >> 6, n = blockIdx.x & 63, tid = threadIdx.x;
    const float* W = (m == 0) ? Wq : ((m == 1) ? Wk : Wv);
    const float sc = (m == 0) ? 1.4426950408889634f : 1.f;
    const int k0 = tid * 4;
    us4 hv, lv;
#pragma unroll
    for (int r = 0; r < 4; ++r) {
        float v = W[(size_t)(k0 + r) * 64 + n] * sc;
        unsigned short hh = bf16rn(v);
        hv[r] = hh;
        lv[r] = bf16rn(v - bf16tof(hh));
    }
    *(us4*)&WT[((size_t)(m * 2 + 0) * 64 + n) * 1024 + k0] = hv;
    *(us4*)&WT[((size_t)(m * 2 + 1) * 64 + n) * 1024 + k0] = lv;
}

// ---------------------------------------------------------------------------
// zero dcol (ws is re-poisoned to 0xAA before every timed launch)
// ---------------------------------------------------------------------------
__global__ void zero_kernel(float* __restrict__ p) {
    p[blockIdx.x * 256 + threadIdx.x] = 0.f;
}

// ---------------------------------------------------------------------------
// Kernel 1: QKV.  64 rows/block (grid 512 -> 2 blocks/CU), 4 waves of 16 rows.
// q,k SWAPPED (D[n][t] = Wt x^T), 3-pass hi/lo -> qhl/khl[b][t][part][64].
// v normal (D[t][d]), single hi pass -> vT[b][d][t] bf16.   (unchanged r5)
// ---------------------------------------------------------------------------
__global__ __launch_bounds__(256, 2) void qkv_kernel(
    const float* __restrict__ x,
    const float* __restrict__ bq, const float* __restrict__ bk,
    const float* __restrict__ bv,
    const short* __restrict__ WT,
    short* __restrict__ qhl, short* __restrict__ khl, short* __restrict__ vT)
{
    __shared__ short xs[8192];    // [part 2][kk 2][row 64][g8 4][8]
    __shared__ short ws[24576];   // [part 2][kk 2][n 192][g8 4][8]
    const int tid = threadIdx.x;
    const int w = tid >> 6, l15 = tid & 15, g = (tid >> 4) & 3;
    const int t0 = blockIdx.x * 64;

    f32x4 acc[12];
    const f32x4 z = {0.f, 0.f, 0.f, 0.f};
#pragma unroll
    for (int i = 0; i < 12; ++i) acc[i] = z;

#pragma unroll 1
    for (int kc = 0; kc < 16; ++kc) {
#pragma unroll
        for (int p = 0; p < 12; ++p) {
            int u = tid + p * 256;
            int part = u / 1536; int r = u - part * 1536;
            int kk = r / 768;    int r2 = r - kk * 768;
            int n = r2 >> 2, g8 = r2 & 3;
            int m = n >> 6, nn = n & 63;
            const short* src = WT + (((size_t)((m * 2 + part) * 64 + nn)) << 10)
                                  + kc * 64 + kk * 32 + g8 * 8;
            gll16(src, &ws[((tid & ~63) + p * 256) * 8]);
        }
#pragma unroll
        for (int p = 0; p < 2; ++p) {
            int idx = tid + p * 256;
            int kk = idx >> 8; int rem = idx & 255;
            int row = rem >> 2, g8 = rem & 3;
            const float* xp = x + (size_t)(t0 + row) * 1024 + kc * 64 + kk * 32 + g8 * 8;
            f32x4 a = *(const f32x4*)xp;
            f32x4 b2 = *(const f32x4*)(xp + 4);
            short8 h8, l8;
#pragma unroll
            for (int j = 0; j < 4; ++j) {
                unsigned short hh = bf16rn(a[j]);
                h8[j] = (short)hh; l8[j] = (short)bf16rn(a[j] - bf16tof(hh));
                hh = bf16rn(b2[j]);
                h8[j + 4] = (short)hh; l8[j + 4] = (short)bf16rn(b2[j] - bf16tof(hh));
            }
            *(short8*)&xs[((kk * 64 + row) * 4 + g8) * 8] = h8;
            *(short8*)&xs[(((2 + kk) * 64 + row) * 4 + g8) * 8] = l8;
        }
        __syncthreads();

#pragma unroll
        for (int kk = 0; kk < 2; ++kk) {
            short8 xf[2];
#pragma unroll
            for (int part = 0; part < 2; ++part)
                xf[part] = *(const short8*)
                    &xs[(((part * 2 + kk) * 64 + w * 16 + l15) * 4 + g) * 8];
#pragma unroll
            for (int Nb = 0; Nb < 12; ++Nb) {
                short8 wh = *(const short8*)&ws[((kk * 192 + Nb * 16 + l15) * 4 + g) * 8];
                if (Nb < 8) {
                    short8 wl = *(const short8*)
                        &ws[(((2 + kk) * 192 + Nb * 16 + l15) * 4 + g) * 8];
                    acc[Nb] = MFMA16(wh, xf[0], acc[Nb]);
                    acc[Nb] = MFMA16(wh, xf[1], acc[Nb]);
                    acc[Nb] = MFMA16(wl, xf[0], acc[Nb]);
                } else {
                    acc[Nb] = MFMA16(xf[0], wh, acc[Nb]);
                }
            }
        }
        __syncthreads();
    }

    const float LOG2E = 1.4426950408889634f;
#pragma unroll
    for (int Nb = 0; Nb < 12; ++Nb) {
        f32x4 a = acc[Nb];
        if (Nb < 8) {
            const bool isq = (Nb < 4);
            const int nbase = (Nb & 3) * 16 + g * 4;
            const int trow = t0 + w * 16 + l15;
            const float* bias = isq ? bq : bk;
            us4 hv, lv;
#pragma unroll
            for (int r = 0; r < 4; ++r) {
                float v = a[r] + (isq ? bias[nbase + r] * LOG2E : bias[nbase + r]);
                unsigned short hh = bf16rn(v);
                hv[r] = hh; lv[r] = bf16rn(v - bf16tof(hh));
            }
            short* dst = (isq ? qhl : khl) + ((size_t)trow * 2) * 64 + nbase;
            *(us4*)dst = hv;
            *(us4*)(dst + 64) = lv;
        } else {
            const int d = (Nb - 8) * 16 + l15;
            const int tbase = t0 + w * 16 + g * 4;
            const float bvd = bv[d];
            us4 pk;
#pragma unroll
            for (int r = 0; r < 4; ++r) pk[r] = bf16rn(a[r] + bvd);
            const int b = tbase >> 11, ttl = tbase & 2047;
            *(us4*)&vT[((size_t)(b * 64 + d)) * 2048 + ttl] = pk;
        }
    }
}

// ---------------------------------------------------------------------------
// Kernel 2: column sums D[s] = sum_{t>=s} 2^{S'[t,s]} (fixed ref m=0) AND
// stores P = 2^{S'} bf16 in strip-tile MFMA-B-fragment layout:
// Ptile(b, strip i, ss)[kgs 2][t32][g8 4][8], tile = 4 KB.
// Grid (32 sblk, 4 tchunk, 16 b), partial D via fp32 atomicAdd.
// ---------------------------------------------------------------------------
__global__ __launch_bounds__(256, 4) void colstatsP_kernel(
    const short* __restrict__ qhl, const short* __restrict__ khl,
    float* __restrict__ dcol, short* __restrict__ Pst)
{
    __shared__ short kb[8192];   // [part 2][kk 2][row 64][g8][8]
    __shared__ short qb[8192];
    const int tid = threadIdx.x;
    const int w = tid >> 6, l15 = tid & 15, g = (tid >> 4) & 3;
    const int sblk = blockIdx.x, tc = blockIdx.y, b = blockIdx.z;
    const int tt0 = max(sblk, tc * 8), tt1 = min(32, tc * 8 + 8);
    if (tt0 >= tt1) return;
    const int s0 = sblk * 64;
    const int sl = w * 16 + g * 4;
    const int kgs = w >> 1, g8s = (w & 1) * 2 + (g >> 1), j0 = (g & 1) * 4;

#pragma unroll
    for (int p = 0; p < 4; ++p) {
        int u = tid + p * 256;
        int part = u >> 9, kk = (u >> 8) & 1, row = (u >> 2) & 63, g8 = u & 3;
        gll16(khl + ((size_t)(b * TT + s0 + row) * 2 + part) * 64 + kk * 32 + g8 * 8,
              &kb[((tid & ~63) + p * 256) * 8]);
    }

    short8 kf[2][2];
    float dsl[4] = {0.f, 0.f, 0.f, 0.f};
    const f32x4 z = {0.f, 0.f, 0.f, 0.f};

#pragma unroll 1
    for (int tt = tt0; tt < tt1; ++tt) {
#pragma unroll
        for (int p = 0; p < 4; ++p) {
            int u = tid + p * 256;
            int part = u >> 9, kk = (u >> 8) & 1, row = (u >> 2) & 63, g8 = u & 3;
            gll16(qhl + ((size_t)(b * TT + tt * 64 + row) * 2 + part) * 64 + kk * 32 + g8 * 8,
                  &qb[((tid & ~63) + p * 256) * 8]);
        }
        __syncthreads();
        if (tt == tt0) {
#pragma unroll
            for (int kk = 0; kk < 2; ++kk)
#pragma unroll
                for (int part = 0; part < 2; ++part)
                    kf[kk][part] = *(const short8*)
                        &kb[(((part * 2 + kk) * 64 + w * 16 + l15) * 4 + g) * 8];
        }
#pragma unroll
        for (int tb = 0; tb < 4; ++tb) {
            f32x4 a = z;
#pragma unroll
            for (int kk = 0; kk < 2; ++kk) {
                short8 qh = *(const short8*)&qb[((kk * 64 + tb * 16 + l15) * 4 + g) * 8];
                short8 ql = *(const short8*)&qb[(((2 + kk) * 64 + tb * 16 + l15) * 4 + g) * 8];
                a = MFMA16(kf[kk][0], qh, a);
                a = MFMA16(kf[kk][0], ql, a);
                a = MFMA16(kf[kk][1], qh, a);
            }
            if (tt == sblk) {   // diagonal tile: t_local < s_local -> masked
#pragma unroll
                for (int r = 0; r < 4; ++r)
                    if (tb * 16 + l15 < sl + r) a[r] = -INFINITY;
            }
            us4 pk;
#pragma unroll
            for (int r = 0; r < 4; ++r) {
                float p = exp2f(a[r]);     // exp2(-inf)=0 for masked
                dsl[r] += p;
                pk[r] = bf16rn(p);
            }
            const int strip = tt * 2 + (tb >> 1);
            const int t32 = (tb & 1) * 16 + l15;
            size_t toff = ((size_t)(b * 1056 + strip_base(strip) + sblk)) * 2048
                        + ((kgs * 32 + t32) * 4 + g8s) * 8 + j0;
            *(us4*)&Pst[toff] = pk;
        }
        __syncthreads();
    }
#pragma unroll
    for (int r = 0; r < 4; ++r) {
        float dv = dsl[r];
        dv += __shfl_xor(dv, 1); dv += __shfl_xor(dv, 2);
        dv += __shfl_xor(dv, 4); dv += __shfl_xor(dv, 8);
        dsl[r] = dv;
    }
    if (l15 == 0) {
#pragma unroll
        for (int r = 0; r < 4; ++r)
            atomicAdd(&dcol[(size_t)b * TT + s0 + sl + r], dsl[r]);
    }
}

// ---------------------------------------------------------------------------
// Kernel 2.5: v' = v / D  (normalization folded into V, one mul per element)
// vT2[b][d][s] = vT[b][d][s] / dcol[b][s]
// ---------------------------------------------------------------------------
__global__ void vprep_kernel(const short* __restrict__ vT,
                             const float* __restrict__ dcol,
                             short* __restrict__ vT2)
{
    const int u = blockIdx.x * 256 + threadIdx.x;   // 262144 threads
    const int s8 = u & 255, bd = u >> 8;            // bd in [0,1024)
    const int b = bd >> 6;
    short8 v = *(const short8*)&vT[(size_t)bd * 2048 + s8 * 8];
    f32x4 d0 = *(const f32x4*)&dcol[(size_t)b * TT + s8 * 8];
    f32x4 d1 = *(const f32x4*)&dcol[(size_t)b * TT + s8 * 8 + 4];
    short8 o;
#pragma unroll
    for (int j = 0; j < 4; ++j) {
        o[j]     = (short)bf16rn(bf16tof((unsigned short)v[j])     / d0[j]);
        o[4 + j] = (short)bf16rn(bf16tof((unsigned short)v[4 + j]) / d1[j]);
    }
    *(short8*)&vT2[(size_t)bd * 2048 + s8 * 8] = o;
}

// ---------------------------------------------------------------------------
// Kernel 3: output = pure PV.  Block (p, b) owns strips iA=p, iB=63-p.
// Per s-tile: stage V' + P_A + P_B strip-tiles (4 gll16/thread), MFMA.
// 2-phase double-buffer with raw s_barrier + counted vmcnt(4) so next-tile
// loads stay in flight through the barrier (T3-minimum pattern).
// ---------------------------------------------------------------------------
__global__ __launch_bounds__(256, 4) void attnout_kernel(
    const short* __restrict__ Pst, const short* __restrict__ vT2,
    float* __restrict__ out)
{
    __shared__ short vb[2][4096];    // [kgs 2][d 64][g8 4][8]
    __shared__ short ebA[2][2048];   // [kgs 2][t 32][g8 4][8]
    __shared__ short ebB[2][2048];
    const int tid = threadIdx.x;
    const int w = tid >> 6, l15 = tid & 15, g = (tid >> 4) & 3;
    const int p = blockIdx.x, b = blockIdx.y;
    const int iA = p, iB = 63 - p;
    const int nA = iA >> 1, nB = iB >> 1;
    const int sl = w * 16 + g * 4;

    const short* PA = Pst + ((size_t)(b * 1056 + strip_base(iA))) * 2048;
    const short* PB = Pst + ((size_t)(b * 1056 + strip_base(iB))) * 2048;
    const short* vbase = vT2 + (size_t)b * 64 * 2048;
    const int ldsu = (tid & ~63) * 8;   // wave-uniform LDS unit base (shorts)

    auto stage = [&](int ss, int buf) {
        // V' tile: 2 rounds (8 KB)
#pragma unroll
        for (int pp = 0; pp < 2; ++pp) {
            int u = tid + pp * 256;
            int kgs = u >> 8, d = (u >> 2) & 63, g8 = u & 3;
            gll16(vbase + ((size_t)d) * 2048 + ss * 64 + kgs * 32 + g8 * 8,
                  &vb[buf][ldsu + pp * 2048]);
        }
        // P strip-tiles: 1 round each (4 KB, byte-identical layout copy)
        gll16(PB + (size_t)ss * 2048 + tid * 8, &ebB[buf][ldsu]);
        gll16(PA + (size_t)ss * 2048 + tid * 8, &ebA[buf][ldsu]);  // garbage ok if ss>nA
    };

    f32x4 oaccA[2], oaccB[2];
    const f32x4 z = {0.f, 0.f, 0.f, 0.f};
    oaccA[0] = z; oaccA[1] = z; oaccB[0] = z; oaccB[1] = z;

    stage(0, 0);
#pragma unroll 1
    for (int ss = 0; ss <= nB; ++ss) {
        const int nss = (ss < nB) ? ss + 1 : nB;    // uniform 4-load stage every iter
        stage(nss, (ss + 1) & 1);
        asm volatile("s_waitcnt vmcnt(4)" ::: "memory");
        __builtin_amdgcn_s_barrier();
        asm volatile("" ::: "memory");

        const int cb_ = ss & 1;
        short8 vf[2];
#pragma unroll
        for (int kg = 0; kg < 2; ++kg)
            vf[kg] = *(const short8*)&vb[cb_][((kg * 64 + w * 16 + l15) * 4 + g) * 8];
#pragma unroll
        for (int tb = 0; tb < 2; ++tb)
#pragma unroll
            for (int kg = 0; kg < 2; ++kg) {
                short8 ef = *(const short8*)&ebB[cb_][((kg * 32 + tb * 16 + l15) * 4 + g) * 8];
                oaccB[tb] = MFMA16(vf[kg], ef, oaccB[tb]);
            }
        if (ss <= nA) {
#pragma unroll
            for (int tb = 0; tb < 2; ++tb)
#pragma unroll
                for (int kg = 0; kg < 2; ++kg) {
                    short8 ef = *(const short8*)&ebA[cb_][((kg * 32 + tb * 16 + l15) * 4 + g) * 8];
                    oaccA[tb] = MFMA16(vf[kg], ef, oaccA[tb]);
                }
        }
        asm volatile("" ::: "memory");
        __builtin_amdgcn_s_barrier();
    }

    // O^T D-frag: col = t (l15), row = d = w*16 + g*4 + r -> float4 along d
#pragma unroll
    for (int tb = 0; tb < 2; ++tb) {
        const int tA = iA * 32 + tb * 16 + l15;
        const int tB = iB * 32 + tb * 16 + l15;
        *(f32x4*)(out + ((size_t)(b * TT + tA)) * 64 + sl) = oaccA[tb];
        *(f32x4*)(out + ((size_t)(b * TT + tB)) * 64 + sl) = oaccB[tb];
    }
}

extern "C" void kernel_launch(void* const* d_in, const int* in_sizes, int n_in,
                              void* d_out, int out_size, void* d_ws, size_t ws_size,
                              hipStream_t stream)
{
    const float* x  = (const float*)d_in[0];
    const float* Wq = (const float*)d_in[1];
    const float* bq = (const float*)d_in[2];
    const float* Wk = (const float*)d_in[3];
    const float* bk = (const float*)d_in[4];
    const float* Wv = (const float*)d_in[5];
    const float* bv = (const float*)d_in[6];

    char* wsb = (char*)d_ws;
    short* qhl  = (short*)wsb;                       // 8,388,608 B
    short* khl  = (short*)(wsb + 8388608);           // 8,388,608 B
    short* vTb  = (short*)(wsb + 16777216);          // 4,194,304 B
    short* vT2  = (short*)(wsb + 20971520);          // 4,194,304 B
    short* WT   = (short*)(wsb + 25165824);          //   786,432 B
    float* dcol = (float*)(wsb + 25952256);          //   131,072 B
    short* Pst  = (short*)(wsb + 26083328);          // 69,206,016 B (total ~95.3 MB)

    zero_kernel<<<dim3(128), 256, 0, stream>>>(dcol);
    wprep_kernel<<<dim3(192), 256, 0, stream>>>(Wq, Wk, Wv, WT);
    qkv_kernel<<<dim3(512), 256, 0, stream>>>(x, bq, bk, bv, WT, qhl, khl, vTb);
    colstatsP_kernel<<<dim3(32, 4, NB), 256, 0, stream>>>(qhl, khl, dcol, Pst);
    vprep_kernel<<<dim3(1024), 256, 0, stream>>>(vTb, dcol, vT2);
    attnout_kernel<<<dim3(32, NB), 256, 0, stream>>>(Pst, vT2, (float*)d_out);
}